// Round 5
// baseline (314.147 us; speedup 1.0000x reference)
//
#include <hip/hip_runtime.h>
#include <cstdint>
#include <cstddef>

// DigitCapsule dynamic routing, fp32, fully fused per round.
// x[256,1152,8], W[1152,10,16,8], out v[256,10,16].
// vsum trick: logits at round r = votes . (v0+...+v_{r-1}) -> no logit storage.
// Per round: ONE fused kernel (votes -> logits -> softmax -> weighted sum via
// LDS logit exchange), atomically reduced into s_acc[J][D][B] (160 KB), then a
// tiny squash kernel. No cbuf, no spart.
constexpr int Bn = 256, In = 1152, Pn = 8, Jn = 10, Dn = 16;
constexpr int CA = 6, NCH = In / CA;  // i-chunk per block, 192 chunks
constexpr int JW = 2;                 // j's per wave (5 waves x 2 j = 10)

// One-time transpose x[B][I*P] -> xT[I*P][B] (lane=b coalescing) + zero s_acc.
__global__ __launch_bounds__(256) void xpose_init(const float* __restrict__ x,
                                                  float* __restrict__ xT,
                                                  float* __restrict__ s_acc) {
  __shared__ float tile[64][65];
  const int t = threadIdx.x, r = t >> 6, c = t & 63;
  const int ip0 = blockIdx.x * 64, b0 = blockIdx.y * 64;
  const size_t gid = ((size_t)blockIdx.y * gridDim.x + blockIdx.x) * 256 + t;
  if (gid < (size_t)Jn * Dn * Bn) s_acc[gid] = 0.f;  // 576 blocks cover 40960
  #pragma unroll
  for (int k = 0; k < 16; ++k) {
    const int row = k * 4 + r;
    tile[row][c] = x[(size_t)(b0 + row) * (In * Pn) + ip0 + c];
  }
  __syncthreads();
  #pragma unroll
  for (int k = 0; k < 16; ++k) {
    const int row = k * 4 + r;
    xT[(size_t)(ip0 + row) * Bn + b0 + c] = tile[c][row];
  }
}

// Fused routing step. Block = 320 thr = 5 waves (wave w owns j = {2w, 2w+1}),
// all waves share the same 64 b's. Grid (bgroup=4, chunk=192).
// MODE 0: c uniform (0.1 folded into squash) -> acc = sum votes
// MODE 1: logits = votes.vsum, LDS exchange, softmax -> acc = sum c*votes
template <int MODE>
__global__ __launch_bounds__(320) void capsBA(const float* __restrict__ xT,
                                              const float* __restrict__ w,
                                              const float* __restrict__ vsumT,
                                              float* __restrict__ s_acc) {
  __shared__ float llog[2][Jn][64];  // double-buffered logit exchange (5 KB)
  const int t = threadIdx.x, wv = t >> 6, bl = t & 63;
  const int j0 = wv * JW;
  const int b = blockIdx.x * 64 + bl;
  const int ch = blockIdx.y;

  float vs[JW][Dn];
  if (MODE == 1) {
    #pragma unroll
    for (int jj = 0; jj < JW; ++jj)
      #pragma unroll
      for (int d = 0; d < Dn; ++d)
        vs[jj][d] = vsumT[((size_t)(j0 + jj) * Dn + d) * Bn + b];
  }

  float acc[JW][Dn];
  #pragma unroll
  for (int jj = 0; jj < JW; ++jj)
    #pragma unroll
    for (int d = 0; d < Dn; ++d) acc[jj][d] = 0.f;

  for (int ii = 0; ii < CA; ++ii) {
    const int i = ch * CA + ii;
    const float* xr = xT + (size_t)i * (Pn * Bn) + b;
    float xv[Pn];
    #pragma unroll
    for (int p = 0; p < Pn; ++p) xv[p] = xr[p * Bn];

    float votes[JW][Dn];
    #pragma unroll
    for (int jj = 0; jj < JW; ++jj) {
      const float* wr = w + ((size_t)i * Jn + (j0 + jj)) * (Dn * Pn);
      #pragma unroll
      for (int d = 0; d < Dn; ++d) {
        const float4 w0 = *(const float4*)(wr + d * Pn);
        const float4 w1 = *(const float4*)(wr + d * Pn + 4);
        float dot = w0.x * xv[0];
        dot = fmaf(w0.y, xv[1], dot); dot = fmaf(w0.z, xv[2], dot);
        dot = fmaf(w0.w, xv[3], dot); dot = fmaf(w1.x, xv[4], dot);
        dot = fmaf(w1.y, xv[5], dot); dot = fmaf(w1.z, xv[6], dot);
        dot = fmaf(w1.w, xv[7], dot);
        votes[jj][d] = dot;
      }
    }

    if (MODE == 0) {
      #pragma unroll
      for (int jj = 0; jj < JW; ++jj)
        #pragma unroll
        for (int d = 0; d < Dn; ++d) acc[jj][d] += votes[jj][d];
    } else {
      float l[JW];
      #pragma unroll
      for (int jj = 0; jj < JW; ++jj) {
        float a = votes[jj][0] * vs[jj][0];
        #pragma unroll
        for (int d = 1; d < Dn; ++d) a = fmaf(votes[jj][d], vs[jj][d], a);
        l[jj] = a;
      }
      const int buf = ii & 1;
      llog[buf][j0][bl] = l[0];
      llog[buf][j0 + 1][bl] = l[1];
      __syncthreads();  // single barrier/iter; double buffer protects reuse
      float lm[Jn];
      #pragma unroll
      for (int j = 0; j < Jn; ++j) lm[j] = llog[buf][j][bl];
      float m = lm[0];
      #pragma unroll
      for (int j = 1; j < Jn; ++j) m = fmaxf(m, lm[j]);
      float ssum = 0.f;
      #pragma unroll
      for (int j = 0; j < Jn; ++j) ssum += __expf(lm[j] - m);
      const float inv = 1.f / ssum;
      #pragma unroll
      for (int jj = 0; jj < JW; ++jj) {
        const float c = __expf(l[jj] - m) * inv;
        #pragma unroll
        for (int d = 0; d < Dn; ++d) acc[jj][d] = fmaf(c, votes[jj][d], acc[jj][d]);
      }
    }
  }

  #pragma unroll
  for (int jj = 0; jj < JW; ++jj)
    #pragma unroll
    for (int d = 0; d < Dn; ++d)
      atomicAdd(&s_acc[((size_t)(j0 + jj) * Dn + d) * Bn + b], acc[jj][d]);
}

// Squash + vsum update + s_acc re-zero. Grid (j=10, bgroup=4) x 64 thr.
// MODE 0: vsum = squash(0.1*s) ; MODE 1: vsum += squash(s) ; MODE 2: out.
template <int MODE>
__global__ __launch_bounds__(64) void capsF(float* __restrict__ s_acc,
                                            float* __restrict__ vsumT,
                                            float* __restrict__ out) {
  const int j = blockIdx.x, b = blockIdx.y * 64 + threadIdx.x;
  float sv[Dn], n2 = 0.f;
  #pragma unroll
  for (int d = 0; d < Dn; ++d) {
    float z = s_acc[((size_t)j * Dn + d) * Bn + b];
    if (MODE == 0) z *= 0.1f;  // uniform c folded here
    sv[d] = z;
    n2 = fmaf(z, z, n2);
  }
  const float sc = n2 / (1.f + n2) / sqrtf(n2 + 1e-7f);
  #pragma unroll
  for (int d = 0; d < Dn; ++d) {
    const size_t o = ((size_t)j * Dn + d) * Bn + b;
    if (MODE == 2) {
      out[((size_t)b * Jn + j) * Dn + d] = sv[d] * sc;
    } else {
      if (MODE == 0) vsumT[o] = sv[d] * sc;
      else           vsumT[o] += sv[d] * sc;
      s_acc[o] = 0.f;  // ready for next round's atomics
    }
  }
}

extern "C" void kernel_launch(void* const* d_in, const int* in_sizes, int n_in,
                              void* d_out, int out_size, void* d_ws, size_t ws_size,
                              hipStream_t stream) {
  const float* x = (const float*)d_in[0];  // [256,1152,8]
  const float* w = (const float*)d_in[1];  // [1152,10,16,8]
  float* xT    = (float*)d_ws;                  // [I*P][B]  9.44 MB
  float* s_acc = xT + (size_t)In * Pn * Bn;     // [J][D][B] 160 KB
  float* vsumT = s_acc + (size_t)Jn * Dn * Bn;  // [J][D][B] 160 KB
  float* out = (float*)d_out;                   // [256,10,16]

  dim3 gX((In * Pn) / 64, Bn / 64);  // 144 x 4
  dim3 gBA(Bn / 64, NCH);            // 4 x 192 (chunk slow -> W/L2 sharing)
  dim3 gF(Jn, Bn / 64);              // 10 x 4

  xpose_init<<<gX, 256, 0, stream>>>(x, xT, s_acc);

  capsBA<0><<<gBA, 320, 0, stream>>>(xT, w, nullptr, s_acc);  // sum votes
  capsF<0><<<gF, 64, 0, stream>>>(s_acc, vsumT, nullptr);     // v0

  capsBA<1><<<gBA, 320, 0, stream>>>(xT, w, vsumT, s_acc);    // c1-weighted
  capsF<1><<<gF, 64, 0, stream>>>(s_acc, vsumT, nullptr);     // vsum += v1

  capsBA<1><<<gBA, 320, 0, stream>>>(xT, w, vsumT, s_acc);    // c2-weighted
  capsF<2><<<gF, 64, 0, stream>>>(s_acc, vsumT, out);         // out = v2
}

// Round 6
// 297.881 us; speedup vs baseline: 1.0546x; 1.0546x over previous
//
#include <hip/hip_runtime.h>
#include <cstdint>
#include <cstddef>

// DigitCapsule dynamic routing, fp32. Split barrier-free kernels, b-per-lane,
// atomic s-reduction, software-pipelined loads.
// x[256,1152,8], W[1152,10,16,8], out v[256,10,16].
// vsum trick: logits at round r = votes . (v0+...+v_{r-1}).
constexpr int Bn = 256, In = 1152, Pn = 8, Jn = 10, Dn = 16;
constexpr int CA = 6, NCH = In / CA;  // capsA i-chunk, 192 chunks
constexpr int IB = 2;                 // capsB i's per block

// One-time transpose x[B][I*P] -> xT[I*P][B] (lane=b coalescing) + zero s_acc.
__global__ __launch_bounds__(256) void xpose_init(const float* __restrict__ x,
                                                  float* __restrict__ xT,
                                                  float* __restrict__ s_acc) {
  __shared__ float tile[64][65];
  const int t = threadIdx.x, r = t >> 6, c = t & 63;
  const int ip0 = blockIdx.x * 64, b0 = blockIdx.y * 64;
  const size_t gid = ((size_t)blockIdx.y * gridDim.x + blockIdx.x) * 256 + t;
  if (gid < (size_t)Jn * Dn * Bn) s_acc[gid] = 0.f;  // 576 blocks cover 40960
  #pragma unroll
  for (int k = 0; k < 16; ++k) {
    const int row = k * 4 + r;
    tile[row][c] = x[(size_t)(b0 + row) * (In * Pn) + ip0 + c];
  }
  __syncthreads();
  #pragma unroll
  for (int k = 0; k < 16; ++k) {
    const int row = k * 4 + r;
    xT[(size_t)(ip0 + row) * Bn + b0 + c] = tile[c][row];
  }
}

// capsA: s[b,j,:] += sum_{i in chunk} c*vote(b,i,j,:), atomically into s_acc.
// thread=b, block=(chunk,j). W in LDS, x/c 2-deep pipelined.
// MODE 0: c = 1 (0.1 folded into capsF) ; MODE 1: c from cbuf[j][i][b].
template <int MODE>
__global__ __launch_bounds__(256) void capsA(
    const float* __restrict__ xT, const float* __restrict__ w,
    const float* __restrict__ cbuf, float* __restrict__ s_acc) {
  __shared__ alignas(16) float wlds[CA * 128];  // 3 KB
  const int t = threadIdx.x, b = t;
  const int ch = blockIdx.x, j = blockIdx.y;
  const int i0 = ch * CA;

  if (t < CA * 32) {  // stage 768 dwords as float4, coalesced
    const int row = t >> 5, col = (t & 31) * 4;
    *(float4*)&wlds[row * 128 + col] =
        *(const float4*)(w + ((size_t)(i0 + row) * Jn + j) * 128 + col);
  }
  __syncthreads();

  float s[Dn];
  #pragma unroll
  for (int d = 0; d < Dn; ++d) s[d] = 0.f;

  float xv[2][Pn], cv[2];
  {
    const float* xr = xT + (size_t)i0 * (Pn * Bn) + b;
    #pragma unroll
    for (int p = 0; p < Pn; ++p) xv[0][p] = xr[p * Bn];
    cv[0] = (MODE == 0) ? 1.f : cbuf[((size_t)j * In + i0) * Bn + b];
  }
  #pragma unroll
  for (int ii = 0; ii < CA; ++ii) {
    const int cur = ii & 1, nxt = cur ^ 1;
    if (ii + 1 < CA) {  // prefetch next i's x and c
      const float* xr = xT + (size_t)(i0 + ii + 1) * (Pn * Bn) + b;
      #pragma unroll
      for (int p = 0; p < Pn; ++p) xv[nxt][p] = xr[p * Bn];
      cv[nxt] = (MODE == 0) ? 1.f : cbuf[((size_t)j * In + i0 + ii + 1) * Bn + b];
    }
    float xc[Pn];
    #pragma unroll
    for (int p = 0; p < Pn; ++p)
      xc[p] = (MODE == 0) ? xv[cur][p] : xv[cur][p] * cv[cur];
    const float4* wf = (const float4*)&wlds[ii * 128];
    #pragma unroll
    for (int d = 0; d < Dn; ++d) {
      const float4 w0 = wf[d * 2];      // ds_read_b128 broadcast
      const float4 w1 = wf[d * 2 + 1];
      float dot = w0.x * xc[0];
      dot = fmaf(w0.y, xc[1], dot); dot = fmaf(w0.z, xc[2], dot);
      dot = fmaf(w0.w, xc[3], dot); dot = fmaf(w1.x, xc[4], dot);
      dot = fmaf(w1.y, xc[5], dot); dot = fmaf(w1.z, xc[6], dot);
      dot = fmaf(w1.w, xc[7], dot);
      s[d] += dot;
    }
  }
  #pragma unroll
  for (int d = 0; d < Dn; ++d)
    atomicAdd(&s_acc[((size_t)j * Dn + d) * Bn + b], s[d]);
}

// capsF: squash s_acc, update vsumT, rezero s_acc. Grid (j=10, bgroup=4) x 64.
// MODE 0: vsum = squash(0.1*s) ; MODE 1: vsum += squash(s) ; MODE 2: out.
template <int MODE>
__global__ __launch_bounds__(64) void capsF(float* __restrict__ s_acc,
                                            float* __restrict__ vsumT,
                                            float* __restrict__ out) {
  const int j = blockIdx.x, b = blockIdx.y * 64 + threadIdx.x;
  float sv[Dn], n2 = 0.f;
  #pragma unroll
  for (int d = 0; d < Dn; ++d) {
    float z = s_acc[((size_t)j * Dn + d) * Bn + b];
    if (MODE == 0) z *= 0.1f;  // uniform c folded here
    sv[d] = z;
    n2 = fmaf(z, z, n2);
  }
  const float sc = n2 / (1.f + n2) / sqrtf(n2 + 1e-7f);
  #pragma unroll
  for (int d = 0; d < Dn; ++d) {
    const size_t o = ((size_t)j * Dn + d) * Bn + b;
    if (MODE == 2) {
      out[((size_t)b * Jn + j) * Dn + d] = sv[d] * sc;
    } else {
      if (MODE == 0) vsumT[o] = sv[d] * sc;
      else           vsumT[o] += sv[d] * sc;
      s_acc[o] = 0.f;  // ready for next round's atomics
    }
  }
}

// capsB: l[j] = votes(b,i,j,:).vsum[b,j,:]; c = softmax_j -> cbuf[j][i][b].
// thread=b, block=IB i's, barrier-free j-loop with vsum prefetched one j ahead.
__global__ __launch_bounds__(256) void capsB(
    const float* __restrict__ xT, const float* __restrict__ w,
    const float* __restrict__ vsumT, float* __restrict__ cbuf) {
  __shared__ alignas(16) float wlds[IB * 1280];  // 10 KB
  const int t = threadIdx.x, b = t;
  const int i0 = blockIdx.x * IB;

  #pragma unroll
  for (int k = 0; k < 3; ++k) {  // stage 2560 dwords = 640 float4
    const int e = t + k * 256;
    if (e < IB * 320)
      ((float4*)wlds)[e] = ((const float4*)(w + (size_t)i0 * 1280))[e];
  }
  __syncthreads();

  float xv[IB][Pn];
  #pragma unroll
  for (int ii = 0; ii < IB; ++ii) {
    const float* xr = xT + (size_t)(i0 + ii) * (Pn * Bn) + b;
    #pragma unroll
    for (int p = 0; p < Pn; ++p) xv[ii][p] = xr[p * Bn];
  }

  float vs[2][Dn];
  #pragma unroll
  for (int d = 0; d < Dn; ++d) vs[0][d] = vsumT[(size_t)d * Bn + b];

  float l[IB][Jn];
  #pragma unroll
  for (int j = 0; j < Jn; ++j) {
    const int cur = j & 1, nxt = cur ^ 1;
    if (j + 1 < Jn) {  // prefetch next j's vsum while this j's FMAs run
      #pragma unroll
      for (int d = 0; d < Dn; ++d)
        vs[nxt][d] = vsumT[((size_t)(j + 1) * Dn + d) * Bn + b];
    }
    #pragma unroll
    for (int ii = 0; ii < IB; ++ii) {
      const float4* wf = (const float4*)&wlds[ii * 1280 + j * 128];
      float acc = 0.f;
      #pragma unroll
      for (int d = 0; d < Dn; ++d) {
        const float4 w0 = wf[d * 2];
        const float4 w1 = wf[d * 2 + 1];
        float dot = w0.x * xv[ii][0];
        dot = fmaf(w0.y, xv[ii][1], dot); dot = fmaf(w0.z, xv[ii][2], dot);
        dot = fmaf(w0.w, xv[ii][3], dot); dot = fmaf(w1.x, xv[ii][4], dot);
        dot = fmaf(w1.y, xv[ii][5], dot); dot = fmaf(w1.z, xv[ii][6], dot);
        dot = fmaf(w1.w, xv[ii][7], dot);
        acc = fmaf(dot, vs[cur][d], acc);
      }
      l[ii][j] = acc;
    }
  }

  #pragma unroll
  for (int ii = 0; ii < IB; ++ii) {
    float m = l[ii][0];
    #pragma unroll
    for (int j = 1; j < Jn; ++j) m = fmaxf(m, l[ii][j]);
    float ssum = 0.f;
    #pragma unroll
    for (int j = 0; j < Jn; ++j) { l[ii][j] = __expf(l[ii][j] - m); ssum += l[ii][j]; }
    const float inv = 1.f / ssum;
    #pragma unroll
    for (int j = 0; j < Jn; ++j)
      cbuf[((size_t)j * In + (i0 + ii)) * Bn + b] = l[ii][j] * inv;
  }
}

extern "C" void kernel_launch(void* const* d_in, const int* in_sizes, int n_in,
                              void* d_out, int out_size, void* d_ws, size_t ws_size,
                              hipStream_t stream) {
  const float* x = (const float*)d_in[0];  // [256,1152,8]
  const float* w = (const float*)d_in[1];  // [1152,10,16,8]
  float* xT    = (float*)d_ws;                  // [I*P][B]  9.44 MB
  float* s_acc = xT + (size_t)In * Pn * Bn;     // [J][D][B] 160 KB
  float* vsumT = s_acc + (size_t)Jn * Dn * Bn;  // [J][D][B] 160 KB
  float* cbuf  = vsumT + (size_t)Jn * Dn * Bn;  // [J][I][B] 11.8 MB
  float* out = (float*)d_out;                   // [256,10,16]

  dim3 gX((In * Pn) / 64, Bn / 64);  // 144 x 4
  dim3 gA(NCH, Jn);                  // 192 x 10 = 1920 blocks
  dim3 gF(Jn, Bn / 64);              // 10 x 4
  const int gB = In / IB;            // 576 blocks

  xpose_init<<<gX, 256, 0, stream>>>(x, xT, s_acc);

  capsA<0><<<gA, 256, 0, stream>>>(xT, w, nullptr, s_acc);  // sum votes
  capsF<0><<<gF, 64, 0, stream>>>(s_acc, vsumT, nullptr);   // v0 (0.1 folded)

  capsB<<<gB, 256, 0, stream>>>(xT, w, vsumT, cbuf);        // c1
  capsA<1><<<gA, 256, 0, stream>>>(xT, w, cbuf, s_acc);
  capsF<1><<<gF, 64, 0, stream>>>(s_acc, vsumT, nullptr);   // vsum += v1

  capsB<<<gB, 256, 0, stream>>>(xT, w, vsumT, cbuf);        // c2
  capsA<1><<<gA, 256, 0, stream>>>(xT, w, cbuf, s_acc);
  capsF<2><<<gF, 64, 0, stream>>>(s_acc, vsumT, out);       // out = v2
}